// Round 23
// baseline (77.385 us; speedup 1.0000x reference)
//
#include <hip/hip_runtime.h>
#include <hip/hip_bf16.h>

#define S_ 1024
#define H_ 16

typedef __attribute__((ext_vector_type(4))) float f32x4;
typedef __attribute__((ext_vector_type(8))) __bf16 bf16x8;
typedef __attribute__((ext_vector_type(4))) unsigned short ushort4v;

// native RTNE f32->bf16 (compiler emits v_cvt_pk_bf16_f32)
static __device__ __forceinline__ unsigned short f2bf(float f) {
  union { __bf16 h; unsigned short u; } x;
  x.h = (__bf16)f;
  return x.u;
}

static __device__ __forceinline__ void gload16(const void* g, void* l) {
  __builtin_amdgcn_global_load_lds(
      (const __attribute__((address_space(1))) void*)g,
      (__attribute__((address_space(3))) void*)l, 16, 0, 0);
}

// ---------------------------------------------------------------- fused prep:
// blocks [0,4096): hs f32 -> bf16 A ; [4096,7168): att_w^T -> W1t ; [7168,8192): out_w^T -> W2t
static __device__ __forceinline__ void tcvt_body(const float* __restrict__ in,
                                                 unsigned short* __restrict__ out,
                                                 int R, int C, int blk) {
  __shared__ float t[32][33];
  int nc = C >> 5;
  int tr = blk / nc, tc = blk % nc;
  int r0 = tr * 32, c0 = tc * 32;
  int tx = threadIdx.x & 31, ty = threadIdx.x >> 5;  // ty 0..7
  for (int i = 0; i < 4; ++i)
    t[ty + i * 8][tx] = in[(size_t)(r0 + ty + i * 8) * C + c0 + tx];
  __syncthreads();
  for (int i = 0; i < 4; ++i)
    out[(size_t)(c0 + ty + i * 8) * R + r0 + tx] = f2bf(t[tx][ty + i * 8]);
}

__global__ void k_prep(const float* __restrict__ hs,
                       const float* __restrict__ att_w,
                       const float* __restrict__ out_w,
                       unsigned short* __restrict__ A,
                       unsigned short* __restrict__ W1t,
                       unsigned short* __restrict__ W2t) {
  const int blk = blockIdx.x;
  if (blk < 4096) {
    int i = (blk * 256 + threadIdx.x) * 4;
    f32x4 v = *(const f32x4*)(hs + i);
    ushort4v o;
    for (int j = 0; j < 4; ++j) o[j] = f2bf(v[j]);
    *(ushort4v*)(A + i) = o;
  } else if (blk < 4096 + 3072) {
    tcvt_body(att_w, W1t, 1024, 3072, blk - 4096);
  } else {
    tcvt_body(out_w, W2t, 1024, 1024, blk - 7168);
  }
}

// ---------------------------------------------------------------- GEMM1  (128x128, BK=64)
// R19 late-stage single-buffer loop. R23: 2D XCD chunking — each XCD's 96-block chunk
// covers 8 tm x 12 tn (L2 working set 2MB A + 3MB B = 5MB, vs 4tm x 24tn = 7MB which
// thrashed W1t and gave 40MB FETCH). Bijective: chunk = bid&7, idx = bid>>3.
// QSC: scale output cols < 1024 by 0.125*log2(e). VOUT: cols >= 2048 transposed to Vt.
template<int OUTF32, int QSC, int VOUT>
__global__ __launch_bounds__(256, 2)
void k_gemm_bt(const unsigned short* __restrict__ A,
               const unsigned short* __restrict__ Bt,
               const float* __restrict__ bias,
               void* __restrict__ C,
               unsigned short* __restrict__ Vt,
               int M, int N, int K, int ldc) {
  __shared__ __attribute__((aligned(16))) unsigned short As[128 * 64];
  __shared__ __attribute__((aligned(16))) unsigned short Bs[128 * 64];
  const int lane = threadIdx.x & 63;
  const int wv = threadIdx.x >> 6;
  // 2D XCD chunking (grid = 32 tm x 24 tn = 768, 8 chunks of 96 = 8tm x 12tn)
  const int chunk = blockIdx.x & 7;
  const int idx = blockIdx.x >> 3;          // 0..95
  const int tm = (chunk >> 1) * 8 + idx / 12;
  const int tn = (chunk & 1) * 12 + idx % 12;
  const int r8 = lane >> 3, c8 = lane & 7;
  const int wr = (wv >> 1) * 64, wc = (wv & 1) * 64;
  const int l15 = lane & 15, lh = lane >> 4;

  f32x4 acc[4][4] = {};
  const int nkt = K >> 6;   // 16 for K=1024

#define GSTAGE(t)                                                                      \
  do {                                                                                 \
    const int kb_ = (t) * 64;                                                          \
    for (int i = 0; i < 4; ++i) {                                                      \
      int row = wv * 32 + i * 8 + r8;                                                  \
      int col = kb_ + ((c8 ^ (row & 7)) << 3);                                         \
      gload16(A + (size_t)(tm * 128 + row) * K + col, &As[(wv * 32 + i * 8) * 64]);    \
      gload16(Bt + (size_t)(tn * 128 + row) * K + col, &Bs[(wv * 32 + i * 8) * 64]);   \
    }                                                                                  \
  } while (0)

  GSTAGE(0);
  for (int kt = 0; kt < nkt; ++kt) {
    asm volatile("s_waitcnt vmcnt(0)" ::: "memory");   // stage(kt) landed
    __builtin_amdgcn_s_barrier();

    bf16x8 af[2][4], bfr[2][4];
#pragma unroll
    for (int kk = 0; kk < 2; ++kk)
#pragma unroll
      for (int mi = 0; mi < 4; ++mi) {
        int rowa = wr + mi * 16 + l15;
        int cola = (kk * 32 + lh * 8) ^ ((rowa & 7) << 3);
        af[kk][mi] = *(const bf16x8*)&As[rowa * 64 + cola];
        int rowb = wc + mi * 16 + l15;
        int colb = (kk * 32 + lh * 8) ^ ((rowb & 7) << 3);
        bfr[kk][mi] = *(const bf16x8*)&Bs[rowb * 64 + colb];
      }
    asm volatile("s_waitcnt lgkmcnt(0)" ::: "memory"); // my reads of the buffer complete
    __builtin_amdgcn_s_barrier();                       // all waves done reading
    if (kt + 1 < nkt) GSTAGE(kt + 1);                   // refill; flight overlaps MFMAs

    __builtin_amdgcn_s_setprio(1);
#pragma unroll
    for (int kk = 0; kk < 2; ++kk)
#pragma unroll
      for (int mi = 0; mi < 4; ++mi)
#pragma unroll
        for (int ni = 0; ni < 4; ++ni)
          acc[mi][ni] = __builtin_amdgcn_mfma_f32_16x16x32_bf16(af[kk][mi], bfr[kk][ni], acc[mi][ni], 0, 0, 0);
    __builtin_amdgcn_s_setprio(0);
  }
#undef GSTAGE

  float bv[4];
  for (int ni = 0; ni < 4; ++ni) bv[ni] = bias[tn * 128 + wc + ni * 16 + l15];

  if (VOUT && tn * 128 >= 2048) {
#pragma unroll
    for (int mi = 0; mi < 4; ++mi) {
      int tok0 = tm * 128 + wr + mi * 16 + lh * 4;
      size_t b_ = tok0 >> 10, s_ = tok0 & 1023;
#pragma unroll
      for (int ni = 0; ni < 4; ++ni) {
        int dg = tn * 128 + wc + ni * 16 + l15 - 2048;   // 0..1023
        ushort4v pk;
#pragma unroll
        for (int r = 0; r < 4; ++r) pk[r] = f2bf(acc[mi][ni][r] + bv[ni]);
        *(ushort4v*)&Vt[(b_ << 20) + ((size_t)dg << 10) + s_] = pk;
      }
    }
    return;
  }

  for (int mi = 0; mi < 4; ++mi)
    for (int r = 0; r < 4; ++r) {
      size_t grow = tm * 128 + wr + mi * 16 + lh * 4 + r;   // C/D: col=lane&15, row=(lane>>4)*4+reg
      for (int ni = 0; ni < 4; ++ni) {
        int gcol = tn * 128 + wc + ni * 16 + l15;
        float v = acc[mi][ni][r] + bv[ni];
        if (QSC && gcol < 1024) v *= 0.18033688f;  // 0.125*log2(e)
        if (OUTF32) ((float*)C)[grow * ldc + gcol] = v;
        else        ((unsigned short*)C)[grow * ldc + gcol] = f2bf(v);
      }
    }
}

// ---------------------------------------------------------------- GEMM2  (64x128 tile, BK=64)
// 512 blocks = 2 blocks/CU co-resident, 24 KB LDS; W2t (2MB) is L2-resident.
// R19 late-stage skeleton + contiguous-chunk XCD swizzle.
__global__ __launch_bounds__(256, 2)
void k_gemm2(const unsigned short* __restrict__ A,
             const unsigned short* __restrict__ Bt,
             const float* __restrict__ bias,
             float* __restrict__ C,
             int M, int N, int K) {
  __shared__ __attribute__((aligned(16))) unsigned short As[64 * 64];
  __shared__ __attribute__((aligned(16))) unsigned short Bs[128 * 64];
  const int lane = threadIdx.x & 63;
  const int wv = threadIdx.x >> 6;
  const int nTn = N >> 7;                 // 8
  const int cpx = gridDim.x >> 3;
  const int wg = (blockIdx.x & 7) * cpx + (blockIdx.x >> 3);
  const int tm = wg / nTn;
  const int tn = wg % nTn;
  const int r8 = lane >> 3, c8 = lane & 7;
  const int wr = (wv >> 1) * 32, wc = (wv & 1) * 64;
  const int l15 = lane & 15, lh = lane >> 4;

  f32x4 acc[2][4] = {};
  const int nkt = K >> 6;   // 16

#define GSTAGE2(t)                                                                     \
  do {                                                                                 \
    const int kb_ = (t) * 64;                                                          \
    for (int i = 0; i < 2; ++i) {        /* A: 64 rows */                              \
      int row = wv * 16 + i * 8 + r8;                                                  \
      int col = kb_ + ((c8 ^ (row & 7)) << 3);                                         \
      gload16(A + (size_t)(tm * 64 + row) * K + col, &As[(wv * 16 + i * 8) * 64]);     \
    }                                                                                  \
    for (int i = 0; i < 4; ++i) {        /* B: 128 rows */                             \
      int row = wv * 32 + i * 8 + r8;                                                  \
      int col = kb_ + ((c8 ^ (row & 7)) << 3);                                         \
      gload16(Bt + (size_t)(tn * 128 + row) * K + col, &Bs[(wv * 32 + i * 8) * 64]);   \
    }                                                                                  \
  } while (0)

  GSTAGE2(0);
  for (int kt = 0; kt < nkt; ++kt) {
    asm volatile("s_waitcnt vmcnt(0)" ::: "memory");
    __builtin_amdgcn_s_barrier();

    bf16x8 af[2][2], bfr[2][4];
#pragma unroll
    for (int kk = 0; kk < 2; ++kk) {
#pragma unroll
      for (int mi = 0; mi < 2; ++mi) {
        int rowa = wr + mi * 16 + l15;
        int cola = (kk * 32 + lh * 8) ^ ((rowa & 7) << 3);
        af[kk][mi] = *(const bf16x8*)&As[rowa * 64 + cola];
      }
#pragma unroll
      for (int ni = 0; ni < 4; ++ni) {
        int rowb = wc + ni * 16 + l15;
        int colb = (kk * 32 + lh * 8) ^ ((rowb & 7) << 3);
        bfr[kk][ni] = *(const bf16x8*)&Bs[rowb * 64 + colb];
      }
    }
    asm volatile("s_waitcnt lgkmcnt(0)" ::: "memory");
    __builtin_amdgcn_s_barrier();
    if (kt + 1 < nkt) GSTAGE2(kt + 1);

    __builtin_amdgcn_s_setprio(1);
#pragma unroll
    for (int kk = 0; kk < 2; ++kk)
#pragma unroll
      for (int mi = 0; mi < 2; ++mi)
#pragma unroll
        for (int ni = 0; ni < 4; ++ni)
          acc[mi][ni] = __builtin_amdgcn_mfma_f32_16x16x32_bf16(af[kk][mi], bfr[kk][ni], acc[mi][ni], 0, 0, 0);
    __builtin_amdgcn_s_setprio(0);
  }
#undef GSTAGE2

  float bv[4];
#pragma unroll
  for (int ni = 0; ni < 4; ++ni) bv[ni] = bias[tn * 128 + wc + ni * 16 + l15];
#pragma unroll
  for (int mi = 0; mi < 2; ++mi)
#pragma unroll
    for (int r = 0; r < 4; ++r) {
      size_t grow = tm * 64 + wr + mi * 16 + lh * 4 + r;
#pragma unroll
      for (int ni = 0; ni < 4; ++ni) {
        int gcol = tn * 128 + wc + ni * 16 + l15;
        C[grow * N + gcol] = acc[mi][ni][r] + bv[ni];
      }
    }
}

// ---------------------------------------------------------------- flash attention (paired q-tiles,
// no-max softmax + ones-MFMA row-sum + depth-2 counted-vmcnt ring + DUAL P buffers).
// Q is pre-scaled by 0.125*log2(e) in GEMM1, so P = exp2(q.k) directly.
// qkv here is the QK buffer: [4096 tokens][2048] (Q cols 0..1023, K cols 1024..2047).
template<bool DIAG>
static __device__ __forceinline__ void attn_tile(
    const bf16x8 qf[2], const bf16x8 kf[2][4], const bf16x8 vf[2][4], bf16x8 onef,
    unsigned short* __restrict__ Pw, f32x4 o[4], f32x4* lacc,
    int q_lo, int k0, int l15, int lh) {
  f32x4 sc[4] = {};
  __builtin_amdgcn_s_setprio(1);
#pragma unroll
  for (int kk = 0; kk < 2; ++kk)
#pragma unroll
    for (int ni = 0; ni < 4; ++ni)
      sc[ni] = __builtin_amdgcn_mfma_f32_16x16x32_bf16(qf[kk], kf[kk][ni], sc[ni], 0, 0, 0);
  __builtin_amdgcn_s_setprio(0);
#pragma unroll
  for (int ni = 0; ni < 4; ++ni) {
    const int kpos = k0 + ni * 16 + l15;
#pragma unroll
    for (int r = 0; r < 4; ++r) {
      const int row = lh * 4 + r;
      float p = __builtin_amdgcn_exp2f(sc[ni][r]);
      if (DIAG && kpos > q_lo + row) p = 0.f;
      Pw[row * 64 + ((ni * 16 + l15) ^ ((row & 7) << 3))] = f2bf(p);
    }
  }
  __builtin_amdgcn_s_setprio(1);
#pragma unroll
  for (int kk = 0; kk < 2; ++kk) {
    int pcol = (kk * 32 + lh * 8) ^ ((l15 & 7) << 3);
    bf16x8 pf = *(const bf16x8*)&Pw[l15 * 64 + pcol];
#pragma unroll
    for (int ni = 0; ni < 4; ++ni)
      o[ni] = __builtin_amdgcn_mfma_f32_16x16x32_bf16(pf, vf[kk][ni], o[ni], 0, 0, 0);
    *lacc = __builtin_amdgcn_mfma_f32_16x16x32_bf16(pf, onef, *lacc, 0, 0, 0);
  }
  __builtin_amdgcn_s_setprio(0);
}

__global__ __launch_bounds__(256, 2)
void k_attn(const unsigned short* __restrict__ qkv,
            const unsigned short* __restrict__ Vt,
            unsigned short* __restrict__ ctx) {
  __shared__ __attribute__((aligned(16))) unsigned short Ks[2][64 * 64];
  __shared__ __attribute__((aligned(16))) unsigned short Vs[2][64 * 64];
  __shared__ __attribute__((aligned(16))) unsigned short Ps[8][16 * 64];  // [wv]=B, [wv+4]=A
  const int lane = threadIdx.x & 63;
  const int wv = threadIdx.x >> 6;
  const int bid = blockIdx.x;
  const int p = bid >> 6;                 // 0..7
  const int g = ((bid >> 3) & 7) * 8 + (bid & 7);  // 0..63, g%8 == bid%8
  const int h = g & 15;
  const int b = g >> 4;
  const int qtA = p, qtB = 15 - p;
  const int r8 = lane >> 3, c8 = lane & 7;
  const int l15 = lane & 15, lh = lane >> 4;

  for (int i = 0; i < 2; ++i) {
    int row = wv * 16 + i * 8 + r8;
    int col = (c8 ^ (row & 7)) << 3;
    gload16(qkv + (size_t)(b * S_ + qtA * 64 + row) * 2048 + h * 64 + col, &Ks[0][(wv * 16 + i * 8) * 64]);
    gload16(qkv + (size_t)(b * S_ + qtB * 64 + row) * 2048 + h * 64 + col, &Ks[1][(wv * 16 + i * 8) * 64]);
  }
  __syncthreads();
  bf16x8 qfA[2], qfB[2];
#pragma unroll
  for (int kk = 0; kk < 2; ++kk) {
    int row = wv * 16 + l15;
    int col = (kk * 32 + lh * 8) ^ ((row & 7) << 3);
    qfA[kk] = *(const bf16x8*)&Ks[0][row * 64 + col];
    qfB[kk] = *(const bf16x8*)&Ks[1][row * 64 + col];
  }
  __syncthreads();

  bf16x8 onef;
#pragma unroll
  for (int j = 0; j < 8; ++j) onef[j] = (__bf16)1.0f;

  f32x4 oA[4] = {}, oB[4] = {}, lA = {}, lB = {};

  const int ntB = qtB + 1;   // >= 9

#define STAGE(t, j)                                                                     \
  do {                                                                                  \
    const int k0s = (t) * 64;                                                           \
    for (int i = 0; i < 2; ++i) {                                                       \
      int row = wv * 16 + i * 8 + r8;                                                   \
      int col = (c8 ^ (row & 7)) << 3;                                                  \
      gload16(qkv + (size_t)(b * S_ + k0s + row) * 2048 + 1024 + h * 64 + col,          \
              &Ks[j][(wv * 16 + i * 8) * 64]);                                          \
      gload16(Vt + (size_t)((b * H_ + h) * 64 + row) * S_ + k0s + col,                  \
              &Vs[j][(wv * 16 + i * 8) * 64]);                                          \
    }                                                                                   \
  } while (0)

  STAGE(0, 0);
  STAGE(1, 1);

  for (int kt = 0; kt < ntB; ++kt) {
    const int cb = kt & 1;
    if (kt + 1 < ntB) asm volatile("s_waitcnt vmcnt(4)" ::: "memory");
    else              asm volatile("s_waitcnt vmcnt(0)" ::: "memory");
    __builtin_amdgcn_s_barrier();

    const int k0 = kt * 64;
    bf16x8 kf[2][4], vf[2][4];
#pragma unroll
    for (int kk = 0; kk < 2; ++kk)
#pragma unroll
      for (int ni = 0; ni < 4; ++ni) {
        int row = ni * 16 + l15;
        int col = (kk * 32 + lh * 8) ^ ((row & 7) << 3);
        kf[kk][ni] = *(const bf16x8*)&Ks[cb][row * 64 + col];
        vf[kk][ni] = *(const bf16x8*)&Vs[cb][row * 64 + col];
      }
    asm volatile("s_waitcnt lgkmcnt(0)" ::: "memory");
    __builtin_amdgcn_s_barrier();
    if (kt + 2 < ntB) STAGE(kt + 2, cb);

    if (kt == qtB)
      attn_tile<true >(qfB, kf, vf, onef, Ps[wv], oB, &lB, qtB * 64 + wv * 16, k0, l15, lh);
    else
      attn_tile<false>(qfB, kf, vf, onef, Ps[wv], oB, &lB, qtB * 64 + wv * 16, k0, l15, lh);
    if (kt < qtA)
      attn_tile<false>(qfA, kf, vf, onef, Ps[wv + 4], oA, &lA, qtA * 64 + wv * 16, k0, l15, lh);
    else if (kt == qtA)
      attn_tile<true >(qfA, kf, vf, onef, Ps[wv + 4], oA, &lA, qtA * 64 + wv * 16, k0, l15, lh);
  }
#undef STAGE

#pragma unroll
  for (int r = 0; r < 4; ++r) {
    float invA = 1.f / lA[r], invB = 1.f / lB[r];
    size_t tokA = (size_t)b * S_ + qtA * 64 + wv * 16 + lh * 4 + r;
    size_t tokB = (size_t)b * S_ + qtB * 64 + wv * 16 + lh * 4 + r;
#pragma unroll
    for (int ni = 0; ni < 4; ++ni) {
      int col = h * 64 + ni * 16 + l15;
      ctx[tokA * 1024 + col] = f2bf(oA[ni][r] * invA);
      ctx[tokB * 1024 + col] = f2bf(oB[ni][r] * invB);
    }
  }
}

// ---------------------------------------------------------------- launch
extern "C" void kernel_launch(void* const* d_in, const int* in_sizes, int n_in,
                              void* d_out, int out_size, void* d_ws, size_t ws_size,
                              hipStream_t stream) {
  const float* hs    = (const float*)d_in[0];
  const float* att_w = (const float*)d_in[1];
  const float* att_b = (const float*)d_in[2];
  const float* out_w = (const float*)d_in[3];
  const float* out_b = (const float*)d_in[4];
  float* out = (float*)d_out;
  char* ws = (char*)d_ws;

  unsigned short* A   = (unsigned short*)(ws);                       // 8 MiB  (hs bf16 [4096][1024])
  unsigned short* W1t = (unsigned short*)(ws + (8ull  << 20));       // 6 MiB  (att_w^T [3072][1024])
  unsigned short* W2t = (unsigned short*)(ws + (14ull << 20));       // 2 MiB  (out_w^T [1024][1024])
  unsigned short* QK  = (unsigned short*)(ws + (16ull << 20));       // 16 MiB ([4096][2048] Q,K only)
  unsigned short* Vt  = (unsigned short*)(ws + (40ull << 20));       // 8 MiB  ([64][64][1024])
  unsigned short* CTX = (unsigned short*)(ws + (48ull << 20));       // 8 MiB  ([4096][1024])

  k_prep<<<8192, 256, 0, stream>>>(hs, att_w, out_w, A, W1t, W2t);
  // GEMM1: 128x128 tile, 768 blocks; Q,K -> QK (ldc=2048, q pre-scaled); V -> Vt transposed.
  k_gemm_bt<0, 1, 1><<<32 * 24, 256, 0, stream>>>(A, W1t, att_b, QK, Vt, 4096, 3072, 1024, 2048);
  k_attn<<<512, 256, 0, stream>>>(QK, Vt, CTX);
  // GEMM2: 64x128 tile, 512 blocks; f32 out + bias.
  k_gemm2<<<64 * 8, 256, 0, stream>>>(CTX, W2t, out_b, out, 4096, 1024, 1024);
}

// Round 24
// 76.867 us; speedup vs baseline: 1.0067x; 1.0067x over previous
//
#include <hip/hip_runtime.h>
#include <hip/hip_bf16.h>

#define S_ 1024
#define H_ 16

typedef __attribute__((ext_vector_type(4))) float f32x4;
typedef __attribute__((ext_vector_type(8))) __bf16 bf16x8;
typedef __attribute__((ext_vector_type(4))) unsigned short ushort4v;

// native RTNE f32->bf16 (compiler emits v_cvt_pk_bf16_f32)
static __device__ __forceinline__ unsigned short f2bf(float f) {
  union { __bf16 h; unsigned short u; } x;
  x.h = (__bf16)f;
  return x.u;
}

static __device__ __forceinline__ void gload16(const void* g, void* l) {
  __builtin_amdgcn_global_load_lds(
      (const __attribute__((address_space(1))) void*)g,
      (__attribute__((address_space(3))) void*)l, 16, 0, 0);
}

// ---------------------------------------------------------------- fused prep:
// blocks [0,4096): hs f32 -> bf16 A ; [4096,7168): att_w^T -> W1t ; [7168,8192): out_w^T -> W2t
static __device__ __forceinline__ void tcvt_body(const float* __restrict__ in,
                                                 unsigned short* __restrict__ out,
                                                 int R, int C, int blk) {
  __shared__ float t[32][33];
  int nc = C >> 5;
  int tr = blk / nc, tc = blk % nc;
  int r0 = tr * 32, c0 = tc * 32;
  int tx = threadIdx.x & 31, ty = threadIdx.x >> 5;  // ty 0..7
  for (int i = 0; i < 4; ++i)
    t[ty + i * 8][tx] = in[(size_t)(r0 + ty + i * 8) * C + c0 + tx];
  __syncthreads();
  for (int i = 0; i < 4; ++i)
    out[(size_t)(c0 + ty + i * 8) * R + r0 + tx] = f2bf(t[tx][ty + i * 8]);
}

__global__ void k_prep(const float* __restrict__ hs,
                       const float* __restrict__ att_w,
                       const float* __restrict__ out_w,
                       unsigned short* __restrict__ A,
                       unsigned short* __restrict__ W1t,
                       unsigned short* __restrict__ W2t) {
  const int blk = blockIdx.x;
  if (blk < 4096) {
    int i = (blk * 256 + threadIdx.x) * 4;
    f32x4 v = *(const f32x4*)(hs + i);
    ushort4v o;
    for (int j = 0; j < 4; ++j) o[j] = f2bf(v[j]);
    *(ushort4v*)(A + i) = o;
  } else if (blk < 4096 + 3072) {
    tcvt_body(att_w, W1t, 1024, 3072, blk - 4096);
  } else {
    tcvt_body(out_w, W2t, 1024, 1024, blk - 7168);
  }
}

// ---------------------------------------------------------------- GEMM1  (128x128, BK=64)
// R24: asymmetric ring — A double-buffered (issued one FULL iteration early, counted
// vmcnt(4), never drained mid-loop), B single-buffered late-stage (issued after the
// read-barrier, MFMA cluster covers its flight). LDS 48 KB -> 3 blocks/CU = exactly
// the 768-block grid co-resident. Contiguous-chunk XCD swizzle (R22-proven).
// QSC: scale output cols < 1024 by 0.125*log2(e). VOUT: cols >= 2048 transposed to Vt.
template<int OUTF32, int QSC, int VOUT>
__global__ __launch_bounds__(256, 2)
void k_gemm_bt(const unsigned short* __restrict__ A,
               const unsigned short* __restrict__ Bt,
               const float* __restrict__ bias,
               void* __restrict__ C,
               unsigned short* __restrict__ Vt,
               int M, int N, int K, int ldc) {
  __shared__ __attribute__((aligned(16))) unsigned short As[2][128 * 64];  // 32 KB
  __shared__ __attribute__((aligned(16))) unsigned short Bs[128 * 64];     // 16 KB
  const int lane = threadIdx.x & 63;
  const int wv = threadIdx.x >> 6;
  const int nTn = N >> 7;
  const int cpx = gridDim.x >> 3;
  const int wg = (blockIdx.x & 7) * cpx + (blockIdx.x >> 3);
  const int tm = wg / nTn;
  const int tn = wg % nTn;
  const int r8 = lane >> 3, c8 = lane & 7;
  const int wr = (wv >> 1) * 64, wc = (wv & 1) * 64;
  const int l15 = lane & 15, lh = lane >> 4;

  f32x4 acc[4][4] = {};
  const int nkt = K >> 6;   // 16 for K=1024

#define ASTAGE(t)                                                                      \
  do {                                                                                 \
    const int kb_ = (t) * 64;                                                          \
    for (int i = 0; i < 4; ++i) {                                                      \
      int row = wv * 32 + i * 8 + r8;                                                  \
      int col = kb_ + ((c8 ^ (row & 7)) << 3);                                         \
      gload16(A + (size_t)(tm * 128 + row) * K + col,                                  \
              &As[(t) & 1][(wv * 32 + i * 8) * 64]);                                   \
    }                                                                                  \
  } while (0)

#define BSTAGE(t)                                                                      \
  do {                                                                                 \
    const int kb_ = (t) * 64;                                                          \
    for (int i = 0; i < 4; ++i) {                                                      \
      int row = wv * 32 + i * 8 + r8;                                                  \
      int col = kb_ + ((c8 ^ (row & 7)) << 3);                                         \
      gload16(Bt + (size_t)(tn * 128 + row) * K + col, &Bs[(wv * 32 + i * 8) * 64]);   \
    }                                                                                  \
  } while (0)

  // prologue: A(0), B(0)
  ASTAGE(0);
  BSTAGE(0);
  for (int kt = 0; kt < nkt; ++kt) {
    // issue A(kt+1) early (slot (kt+1)&1 freed at iter kt-1's read-barrier);
    // then counted wait: A(kt)+B(kt) complete, A(kt+1)'s 4 loads stay in flight.
    if (kt + 1 < nkt) {
      ASTAGE(kt + 1);
      asm volatile("s_waitcnt vmcnt(4)" ::: "memory");
    } else {
      asm volatile("s_waitcnt vmcnt(0)" ::: "memory");
    }
    __builtin_amdgcn_s_barrier();

    bf16x8 af[2][4], bfr[2][4];
#pragma unroll
    for (int kk = 0; kk < 2; ++kk)
#pragma unroll
      for (int mi = 0; mi < 4; ++mi) {
        int rowa = wr + mi * 16 + l15;
        int cola = (kk * 32 + lh * 8) ^ ((rowa & 7) << 3);
        af[kk][mi] = *(const bf16x8*)&As[kt & 1][rowa * 64 + cola];
        int rowb = wc + mi * 16 + l15;
        int colb = (kk * 32 + lh * 8) ^ ((rowb & 7) << 3);
        bfr[kk][mi] = *(const bf16x8*)&Bs[rowb * 64 + colb];
      }
    asm volatile("s_waitcnt lgkmcnt(0)" ::: "memory"); // my reads of As[kt&1]/Bs complete
    __builtin_amdgcn_s_barrier();                       // all waves done reading
    if (kt + 1 < nkt) BSTAGE(kt + 1);                   // refill B; flight overlaps MFMAs

    __builtin_amdgcn_s_setprio(1);
#pragma unroll
    for (int kk = 0; kk < 2; ++kk)
#pragma unroll
      for (int mi = 0; mi < 4; ++mi)
#pragma unroll
        for (int ni = 0; ni < 4; ++ni)
          acc[mi][ni] = __builtin_amdgcn_mfma_f32_16x16x32_bf16(af[kk][mi], bfr[kk][ni], acc[mi][ni], 0, 0, 0);
    __builtin_amdgcn_s_setprio(0);
  }
#undef ASTAGE
#undef BSTAGE

  float bv[4];
  for (int ni = 0; ni < 4; ++ni) bv[ni] = bias[tn * 128 + wc + ni * 16 + l15];

  if (VOUT && tn * 128 >= 2048) {
#pragma unroll
    for (int mi = 0; mi < 4; ++mi) {
      int tok0 = tm * 128 + wr + mi * 16 + lh * 4;
      size_t b_ = tok0 >> 10, s_ = tok0 & 1023;
#pragma unroll
      for (int ni = 0; ni < 4; ++ni) {
        int dg = tn * 128 + wc + ni * 16 + l15 - 2048;   // 0..1023
        ushort4v pk;
#pragma unroll
        for (int r = 0; r < 4; ++r) pk[r] = f2bf(acc[mi][ni][r] + bv[ni]);
        *(ushort4v*)&Vt[(b_ << 20) + ((size_t)dg << 10) + s_] = pk;
      }
    }
    return;
  }

  for (int mi = 0; mi < 4; ++mi)
    for (int r = 0; r < 4; ++r) {
      size_t grow = tm * 128 + wr + mi * 16 + lh * 4 + r;   // C/D: col=lane&15, row=(lane>>4)*4+reg
      for (int ni = 0; ni < 4; ++ni) {
        int gcol = tn * 128 + wc + ni * 16 + l15;
        float v = acc[mi][ni][r] + bv[ni];
        if (QSC && gcol < 1024) v *= 0.18033688f;  // 0.125*log2(e)
        if (OUTF32) ((float*)C)[grow * ldc + gcol] = v;
        else        ((unsigned short*)C)[grow * ldc + gcol] = f2bf(v);
      }
    }
}

// ---------------------------------------------------------------- GEMM2  (64x128 tile, BK=64)
// 512 blocks = 2 blocks/CU co-resident, 24 KB LDS; W2t (2MB) is L2-resident.
// R19 late-stage skeleton + contiguous-chunk XCD swizzle.
__global__ __launch_bounds__(256, 2)
void k_gemm2(const unsigned short* __restrict__ A,
             const unsigned short* __restrict__ Bt,
             const float* __restrict__ bias,
             float* __restrict__ C,
             int M, int N, int K) {
  __shared__ __attribute__((aligned(16))) unsigned short As[64 * 64];
  __shared__ __attribute__((aligned(16))) unsigned short Bs[128 * 64];
  const int lane = threadIdx.x & 63;
  const int wv = threadIdx.x >> 6;
  const int nTn = N >> 7;                 // 8
  const int cpx = gridDim.x >> 3;
  const int wg = (blockIdx.x & 7) * cpx + (blockIdx.x >> 3);
  const int tm = wg / nTn;
  const int tn = wg % nTn;
  const int r8 = lane >> 3, c8 = lane & 7;
  const int wr = (wv >> 1) * 32, wc = (wv & 1) * 64;
  const int l15 = lane & 15, lh = lane >> 4;

  f32x4 acc[2][4] = {};
  const int nkt = K >> 6;   // 16

#define GSTAGE2(t)                                                                     \
  do {                                                                                 \
    const int kb_ = (t) * 64;                                                          \
    for (int i = 0; i < 2; ++i) {        /* A: 64 rows */                              \
      int row = wv * 16 + i * 8 + r8;                                                  \
      int col = kb_ + ((c8 ^ (row & 7)) << 3);                                         \
      gload16(A + (size_t)(tm * 64 + row) * K + col, &As[(wv * 16 + i * 8) * 64]);     \
    }                                                                                  \
    for (int i = 0; i < 4; ++i) {        /* B: 128 rows */                             \
      int row = wv * 32 + i * 8 + r8;                                                  \
      int col = kb_ + ((c8 ^ (row & 7)) << 3);                                         \
      gload16(Bt + (size_t)(tn * 128 + row) * K + col, &Bs[(wv * 32 + i * 8) * 64]);   \
    }                                                                                  \
  } while (0)

  GSTAGE2(0);
  for (int kt = 0; kt < nkt; ++kt) {
    asm volatile("s_waitcnt vmcnt(0)" ::: "memory");
    __builtin_amdgcn_s_barrier();

    bf16x8 af[2][2], bfr[2][4];
#pragma unroll
    for (int kk = 0; kk < 2; ++kk) {
#pragma unroll
      for (int mi = 0; mi < 2; ++mi) {
        int rowa = wr + mi * 16 + l15;
        int cola = (kk * 32 + lh * 8) ^ ((rowa & 7) << 3);
        af[kk][mi] = *(const bf16x8*)&As[rowa * 64 + cola];
      }
#pragma unroll
      for (int ni = 0; ni < 4; ++ni) {
        int rowb = wc + ni * 16 + l15;
        int colb = (kk * 32 + lh * 8) ^ ((rowb & 7) << 3);
        bfr[kk][ni] = *(const bf16x8*)&Bs[rowb * 64 + colb];
      }
    }
    asm volatile("s_waitcnt lgkmcnt(0)" ::: "memory");
    __builtin_amdgcn_s_barrier();
    if (kt + 1 < nkt) GSTAGE2(kt + 1);

    __builtin_amdgcn_s_setprio(1);
#pragma unroll
    for (int kk = 0; kk < 2; ++kk)
#pragma unroll
      for (int mi = 0; mi < 2; ++mi)
#pragma unroll
        for (int ni = 0; ni < 4; ++ni)
          acc[mi][ni] = __builtin_amdgcn_mfma_f32_16x16x32_bf16(af[kk][mi], bfr[kk][ni], acc[mi][ni], 0, 0, 0);
    __builtin_amdgcn_s_setprio(0);
  }
#undef GSTAGE2

  float bv[4];
#pragma unroll
  for (int ni = 0; ni < 4; ++ni) bv[ni] = bias[tn * 128 + wc + ni * 16 + l15];
#pragma unroll
  for (int mi = 0; mi < 2; ++mi)
#pragma unroll
    for (int r = 0; r < 4; ++r) {
      size_t grow = tm * 64 + wr + mi * 16 + lh * 4 + r;
#pragma unroll
      for (int ni = 0; ni < 4; ++ni) {
        int gcol = tn * 128 + wc + ni * 16 + l15;
        C[grow * N + gcol] = acc[mi][ni][r] + bv[ni];
      }
    }
}

// ---------------------------------------------------------------- flash attention (paired q-tiles,
// no-max softmax + ones-MFMA row-sum + depth-2 counted-vmcnt ring + DUAL P buffers).
// Q is pre-scaled by 0.125*log2(e) in GEMM1, so P = exp2(q.k) directly.
// qkv here is the QK buffer: [4096 tokens][2048] (Q cols 0..1023, K cols 1024..2047).
template<bool DIAG>
static __device__ __forceinline__ void attn_tile(
    const bf16x8 qf[2], const bf16x8 kf[2][4], const bf16x8 vf[2][4], bf16x8 onef,
    unsigned short* __restrict__ Pw, f32x4 o[4], f32x4* lacc,
    int q_lo, int k0, int l15, int lh) {
  f32x4 sc[4] = {};
  __builtin_amdgcn_s_setprio(1);
#pragma unroll
  for (int kk = 0; kk < 2; ++kk)
#pragma unroll
    for (int ni = 0; ni < 4; ++ni)
      sc[ni] = __builtin_amdgcn_mfma_f32_16x16x32_bf16(qf[kk], kf[kk][ni], sc[ni], 0, 0, 0);
  __builtin_amdgcn_s_setprio(0);
#pragma unroll
  for (int ni = 0; ni < 4; ++ni) {
    const int kpos = k0 + ni * 16 + l15;
#pragma unroll
    for (int r = 0; r < 4; ++r) {
      const int row = lh * 4 + r;
      float p = __builtin_amdgcn_exp2f(sc[ni][r]);
      if (DIAG && kpos > q_lo + row) p = 0.f;
      Pw[row * 64 + ((ni * 16 + l15) ^ ((row & 7) << 3))] = f2bf(p);
    }
  }
  __builtin_amdgcn_s_setprio(1);
#pragma unroll
  for (int kk = 0; kk < 2; ++kk) {
    int pcol = (kk * 32 + lh * 8) ^ ((l15 & 7) << 3);
    bf16x8 pf = *(const bf16x8*)&Pw[l15 * 64 + pcol];
#pragma unroll
    for (int ni = 0; ni < 4; ++ni)
      o[ni] = __builtin_amdgcn_mfma_f32_16x16x32_bf16(pf, vf[kk][ni], o[ni], 0, 0, 0);
    *lacc = __builtin_amdgcn_mfma_f32_16x16x32_bf16(pf, onef, *lacc, 0, 0, 0);
  }
  __builtin_amdgcn_s_setprio(0);
}

__global__ __launch_bounds__(256, 2)
void k_attn(const unsigned short* __restrict__ qkv,
            const unsigned short* __restrict__ Vt,
            unsigned short* __restrict__ ctx) {
  __shared__ __attribute__((aligned(16))) unsigned short Ks[2][64 * 64];
  __shared__ __attribute__((aligned(16))) unsigned short Vs[2][64 * 64];
  __shared__ __attribute__((aligned(16))) unsigned short Ps[8][16 * 64];  // [wv]=B, [wv+4]=A
  const int lane = threadIdx.x & 63;
  const int wv = threadIdx.x >> 6;
  const int bid = blockIdx.x;
  const int p = bid >> 6;                 // 0..7
  const int g = ((bid >> 3) & 7) * 8 + (bid & 7);  // 0..63, g%8 == bid%8
  const int h = g & 15;
  const int b = g >> 4;
  const int qtA = p, qtB = 15 - p;
  const int r8 = lane >> 3, c8 = lane & 7;
  const int l15 = lane & 15, lh = lane >> 4;

  for (int i = 0; i < 2; ++i) {
    int row = wv * 16 + i * 8 + r8;
    int col = (c8 ^ (row & 7)) << 3;
    gload16(qkv + (size_t)(b * S_ + qtA * 64 + row) * 2048 + h * 64 + col, &Ks[0][(wv * 16 + i * 8) * 64]);
    gload16(qkv + (size_t)(b * S_ + qtB * 64 + row) * 2048 + h * 64 + col, &Ks[1][(wv * 16 + i * 8) * 64]);
  }
  __syncthreads();
  bf16x8 qfA[2], qfB[2];
#pragma unroll
  for (int kk = 0; kk < 2; ++kk) {
    int row = wv * 16 + l15;
    int col = (kk * 32 + lh * 8) ^ ((row & 7) << 3);
    qfA[kk] = *(const bf16x8*)&Ks[0][row * 64 + col];
    qfB[kk] = *(const bf16x8*)&Ks[1][row * 64 + col];
  }
  __syncthreads();

  bf16x8 onef;
#pragma unroll
  for (int j = 0; j < 8; ++j) onef[j] = (__bf16)1.0f;

  f32x4 oA[4] = {}, oB[4] = {}, lA = {}, lB = {};

  const int ntB = qtB + 1;   // >= 9

#define STAGE(t, j)                                                                     \
  do {                                                                                  \
    const int k0s = (t) * 64;                                                           \
    for (int i = 0; i < 2; ++i) {                                                       \
      int row = wv * 16 + i * 8 + r8;                                                   \
      int col = (c8 ^ (row & 7)) << 3;                                                  \
      gload16(qkv + (size_t)(b * S_ + k0s + row) * 2048 + 1024 + h * 64 + col,          \
              &Ks[j][(wv * 16 + i * 8) * 64]);                                          \
      gload16(Vt + (size_t)((b * H_ + h) * 64 + row) * S_ + k0s + col,                  \
              &Vs[j][(wv * 16 + i * 8) * 64]);                                          \
    }                                                                                   \
  } while (0)

  STAGE(0, 0);
  STAGE(1, 1);

  for (int kt = 0; kt < ntB; ++kt) {
    const int cb = kt & 1;
    if (kt + 1 < ntB) asm volatile("s_waitcnt vmcnt(4)" ::: "memory");
    else              asm volatile("s_waitcnt vmcnt(0)" ::: "memory");
    __builtin_amdgcn_s_barrier();

    const int k0 = kt * 64;
    bf16x8 kf[2][4], vf[2][4];
#pragma unroll
    for (int kk = 0; kk < 2; ++kk)
#pragma unroll
      for (int ni = 0; ni < 4; ++ni) {
        int row = ni * 16 + l15;
        int col = (kk * 32 + lh * 8) ^ ((row & 7) << 3);
        kf[kk][ni] = *(const bf16x8*)&Ks[cb][row * 64 + col];
        vf[kk][ni] = *(const bf16x8*)&Vs[cb][row * 64 + col];
      }
    asm volatile("s_waitcnt lgkmcnt(0)" ::: "memory");
    __builtin_amdgcn_s_barrier();
    if (kt + 2 < ntB) STAGE(kt + 2, cb);

    if (kt == qtB)
      attn_tile<true >(qfB, kf, vf, onef, Ps[wv], oB, &lB, qtB * 64 + wv * 16, k0, l15, lh);
    else
      attn_tile<false>(qfB, kf, vf, onef, Ps[wv], oB, &lB, qtB * 64 + wv * 16, k0, l15, lh);
    if (kt < qtA)
      attn_tile<false>(qfA, kf, vf, onef, Ps[wv + 4], oA, &lA, qtA * 64 + wv * 16, k0, l15, lh);
    else if (kt == qtA)
      attn_tile<true >(qfA, kf, vf, onef, Ps[wv + 4], oA, &lA, qtA * 64 + wv * 16, k0, l15, lh);
  }
#undef STAGE

#pragma unroll
  for (int r = 0; r < 4; ++r) {
    float invA = 1.f / lA[r], invB = 1.f / lB[r];
    size_t tokA = (size_t)b * S_ + qtA * 64 + wv * 16 + lh * 4 + r;
    size_t tokB = (size_t)b * S_ + qtB * 64 + wv * 16 + lh * 4 + r;
#pragma unroll
    for (int ni = 0; ni < 4; ++ni) {
      int col = h * 64 + ni * 16 + l15;
      ctx[tokA * 1024 + col] = f2bf(oA[ni][r] * invA);
      ctx[tokB * 1024 + col] = f2bf(oB[ni][r] * invB);
    }
  }
}

// ---------------------------------------------------------------- launch
extern "C" void kernel_launch(void* const* d_in, const int* in_sizes, int n_in,
                              void* d_out, int out_size, void* d_ws, size_t ws_size,
                              hipStream_t stream) {
  const float* hs    = (const float*)d_in[0];
  const float* att_w = (const float*)d_in[1];
  const float* att_b = (const float*)d_in[2];
  const float* out_w = (const float*)d_in[3];
  const float* out_b = (const float*)d_in[4];
  float* out = (float*)d_out;
  char* ws = (char*)d_ws;

  unsigned short* A   = (unsigned short*)(ws);                       // 8 MiB  (hs bf16 [4096][1024])
  unsigned short* W1t = (unsigned short*)(ws + (8ull  << 20));       // 6 MiB  (att_w^T [3072][1024])
  unsigned short* W2t = (unsigned short*)(ws + (14ull << 20));       // 2 MiB  (out_w^T [1024][1024])
  unsigned short* QK  = (unsigned short*)(ws + (16ull << 20));       // 16 MiB ([4096][2048] Q,K only)
  unsigned short* Vt  = (unsigned short*)(ws + (40ull << 20));       // 8 MiB  ([64][64][1024])
  unsigned short* CTX = (unsigned short*)(ws + (48ull << 20));       // 8 MiB  ([4096][1024])

  k_prep<<<8192, 256, 0, stream>>>(hs, att_w, out_w, A, W1t, W2t);
  // GEMM1: 128x128 tile, 768 blocks; Q,K -> QK (ldc=2048, q pre-scaled); V -> Vt transposed.
  k_gemm_bt<0, 1, 1><<<32 * 24, 256, 0, stream>>>(A, W1t, att_b, QK, Vt, 4096, 3072, 1024, 2048);
  k_attn<<<512, 256, 0, stream>>>(QK, Vt, CTX);
  // GEMM2: 64x128 tile, 512 blocks; f32 out + bias.
  k_gemm2<<<64 * 8, 256, 0, stream>>>(CTX, W2t, out_b, out, 4096, 1024, 1024);
}